// Round 1
// baseline (200.569 us; speedup 1.0000x reference)
//
#include <hip/hip_runtime.h>
#include <hip/hip_cooperative_groups.h>

namespace cg = cooperative_groups;

namespace {
constexpr int Hh = 16;
constexpr int Ll = 1024;
constexpr int Dd = 64;
constexpr int Cc = 64;                   // chunk length
constexpr int NCHUNK = Ll / Cc;          // 16
constexpr float PI_HALF = 1.5707963267948966f;
constexpr float EPSV = 1e-6f;
constexpr int KV_ELEMS = 128 * 64;       // bf16 elems per chunk state [d][f]
constexpr size_t KV_TOTAL_E = (size_t)Hh * NCHUNK * KV_ELEMS;
}

typedef __attribute__((ext_vector_type(8))) short short8;
typedef __attribute__((ext_vector_type(4))) float floatx4;

__device__ __forceinline__ unsigned short f2bf(float x) {
    unsigned int u = __float_as_uint(x);
    unsigned int r = u + 0x7fffu + ((u >> 16) & 1u);
    return (unsigned short)(r >> 16);
}
__device__ __forceinline__ float bf2f(unsigned short b) {
    return __uint_as_float(((unsigned int)b) << 16);
}

// ---------------------------------------------------------------------------
// Single fused cooperative kernel. Grid (NCHUNK, Hh) = 256 blocks, 1 per CU.
// Phase 0: stage q,k,v ONCE: qf->Aq, kf->Bk (and transposed kf^T->Ak),
//          V^T->Bv (+ones row for ksum).
// Phase A: chunk state  S_c[d][f] = sum_j v[j][d]*kf[j][f]  via MFMA
//          (A = Ak = kf^T [f][j], B = Bv = [V^T ; 1] rows n), staged to Cst
//          then coalesced bf16 store to ws.  ksum via ones column.
// grid.sync()
// Phase B: exclusive prefix scan across chunks (fp32 accumulate, bf16 store),
//          distributed 2 chains/thread + ksum chains.
// grid.sync()
// Phase C: load scanned state into Bv cols 64.., ksum into Bk row 64, then
//          GEMM1 (scores + denom) -> mask/rowsum -> GEMM2 -> output.
//          Identical arithmetic to the verified 3-kernel version.
__global__ __launch_bounds__(256)
void cf_fused(const float* __restrict__ qin, const float* __restrict__ kin,
              const float* __restrict__ vin,
              unsigned short* __restrict__ wskv, unsigned short* __restrict__ wsks,
              float* __restrict__ out) {
    const int c = blockIdx.x, h = blockIdx.y;
    const int tid = threadIdx.x;
    constexpr int SA = 200, SB = 136, SV = 200, S1 = 72, SC = 136;
    __shared__ unsigned short Aq[64 * SA];   // [l][0..63 scores | 64..191 qf]
    __shared__ unsigned short Bk[80 * SB];   // [n=j][k=f]; row 64 = ksum; 65..79 = 0
    __shared__ unsigned short Bv[80 * SV];   // [n=d][0..63 V^T | 64..191 S]; row64=1s
    __shared__ unsigned short Ak[128 * S1];  // kf^T [f][j]   (phase A only)
    __shared__ unsigned short Cst[64 * SC];  // staged state [d][f] (phase A only)
    __shared__ unsigned short Ks[128];

    const size_t gbase = ((size_t)h * Ll + (size_t)c * Cc) * Dd;
    const float4* q4 = (const float4*)(qin + gbase);
    const float4* k4 = (const float4*)(kin + gbase);
    const float4* v4 = (const float4*)(vin + gbase);
    #pragma unroll
    for (int i = 0; i < 4; ++i) {
        int e4 = i * 256 + tid;
        int j = e4 >> 4, d4 = (e4 & 15) * 4;
        float th = PI_HALF * (float)(c * Cc + j + 1) * (1.0f / (float)Ll);
        float sj, cj; __sincosf(th, &sj, &cj);
        float4 qv = q4[e4];
        float q0 = fmaxf(qv.x, 0.f), q1 = fmaxf(qv.y, 0.f);
        float q2 = fmaxf(qv.z, 0.f), q3 = fmaxf(qv.w, 0.f);
        *(ushort4*)&Aq[j * SA + 64 + d4] =
            make_ushort4(f2bf(q0 * sj), f2bf(q1 * sj), f2bf(q2 * sj), f2bf(q3 * sj));
        *(ushort4*)&Aq[j * SA + 128 + d4] =
            make_ushort4(f2bf(q0 * cj), f2bf(q1 * cj), f2bf(q2 * cj), f2bf(q3 * cj));
        float4 kx = k4[e4];
        float r0 = fmaxf(kx.x, 0.f), r1 = fmaxf(kx.y, 0.f);
        float r2 = fmaxf(kx.z, 0.f), r3 = fmaxf(kx.w, 0.f);
        unsigned short s0 = f2bf(r0 * sj), s1 = f2bf(r1 * sj);
        unsigned short s2 = f2bf(r2 * sj), s3 = f2bf(r3 * sj);
        unsigned short c0 = f2bf(r0 * cj), c1 = f2bf(r1 * cj);
        unsigned short c2 = f2bf(r2 * cj), c3 = f2bf(r3 * cj);
        *(ushort4*)&Bk[j * SB + d4] = make_ushort4(s0, s1, s2, s3);
        *(ushort4*)&Bk[j * SB + 64 + d4] = make_ushort4(c0, c1, c2, c3);
        Ak[(d4 + 0) * S1 + j] = s0;
        Ak[(d4 + 1) * S1 + j] = s1;
        Ak[(d4 + 2) * S1 + j] = s2;
        Ak[(d4 + 3) * S1 + j] = s3;
        Ak[(64 + d4 + 0) * S1 + j] = c0;
        Ak[(64 + d4 + 1) * S1 + j] = c1;
        Ak[(64 + d4 + 2) * S1 + j] = c2;
        Ak[(64 + d4 + 3) * S1 + j] = c3;
        float4 vx = v4[e4];
        Bv[(d4 + 0) * SV + j] = f2bf(vx.x);
        Bv[(d4 + 1) * SV + j] = f2bf(vx.y);
        Bv[(d4 + 2) * SV + j] = f2bf(vx.z);
        Bv[(d4 + 3) * SV + j] = f2bf(vx.w);
    }
    if (tid < 64) Bv[64 * SV + tid] = 0x3F80;            // ones row (bf16 1.0)
    #pragma unroll
    for (int i = 0; i < 4; ++i) {                        // zero Bv rows 65..79 (j cols)
        int z = i * 256 + tid;
        if (z < 960) Bv[(65 + (z >> 6)) * SV + (z & 63)] = 0;
    }
    #pragma unroll
    for (int i = 0; i < 4; ++i) {                        // zero Bk rows 65..79
        int z = i * 256 + tid;
        if (z < 1020) ((unsigned int*)Bk)[(65 * SB) / 2 + z] = 0u;
    }
    __syncthreads();

    const int wave = tid >> 6, lane = tid & 63;
    const int lrow = lane & 15, quad = lane >> 4;

    // ---- Phase A: chunk sums via MFMA (D[m=f][n=d|ones]) ----
    #pragma unroll
    for (int t = 0; t < 2; ++t) {
        const int ft = wave * 2 + t;                     // f-tile 0..7
        short8 af[2];
        #pragma unroll
        for (int ks = 0; ks < 2; ++ks)
            af[ks] = *(const short8*)&Ak[(ft * 16 + lrow) * S1 + ks * 32 + quad * 8];
        #pragma unroll
        for (int nt = 0; nt < 5; ++nt) {
            floatx4 acc = {0.f, 0.f, 0.f, 0.f};
            #pragma unroll
            for (int ks = 0; ks < 2; ++ks) {
                short8 bf = *(const short8*)&Bv[(nt * 16 + lrow) * SV + ks * 32 + quad * 8];
                acc = __builtin_amdgcn_mfma_f32_16x16x32_bf16(af[ks], bf, acc, 0, 0, 0);
            }
            ushort4 pk = make_ushort4(f2bf(acc[0]), f2bf(acc[1]), f2bf(acc[2]), f2bf(acc[3]));
            if (nt < 4) {
                *(ushort4*)&Cst[(nt * 16 + lrow) * SC + ft * 16 + quad * 4] = pk;
            } else if (lrow == 0) {
                *(ushort4*)&Ks[ft * 16 + quad * 4] = pk;  // ksum column (n=64)
            }
        }
    }
    __syncthreads();
    {
        unsigned short* kvout = wskv + (size_t)(h * NCHUNK + c) * KV_ELEMS;
        #pragma unroll
        for (int i = 0; i < 4; ++i) {
            int idx = i * 256 + tid;
            int row = idx >> 4, c8 = (idx & 15) * 8;
            *(uint4*)(kvout + row * 128 + c8) = *(const uint4*)&Cst[row * SC + c8];
        }
        if (tid < 16)
            *(uint4*)(wsks + (size_t)(h * NCHUNK + c) * 128 + tid * 8) =
                *(const uint4*)&Ks[tid * 8];
    }
    __threadfence();
    cg::this_grid().sync();

    // ---- Phase B: exclusive prefix scan across chunks ----
    {
        const int t4 = c * 256 + tid;                    // 0..4095 within this h
        unsigned short* pbase = wskv + (size_t)h * NCHUNK * KV_ELEMS;
        #pragma unroll
        for (int rep = 0; rep < 2; ++rep) {
            unsigned short* p = pbase + rep * 4096 + t4;
            float run = 0.f;
            #pragma unroll
            for (int cc = 0; cc < NCHUNK; ++cc) {
                float v = bf2f(p[(size_t)cc * KV_ELEMS]);
                p[(size_t)cc * KV_ELEMS] = f2bf(run);
                run += v;
            }
        }
        if (t4 < 128) {
            unsigned short* p = wsks + (size_t)h * NCHUNK * 128 + t4;
            float run = 0.f;
            #pragma unroll
            for (int cc = 0; cc < NCHUNK; ++cc) {
                float v = bf2f(p[cc * 128]);
                p[cc * 128] = f2bf(run);
                run += v;
            }
        }
    }
    __threadfence();
    cg::this_grid().sync();

    // ---- Phase C: load scanned state, then GEMM1 + GEMM2 ----
    {
        const uint4* s4g = (const uint4*)(wskv + (size_t)(h * NCHUNK + c) * KV_ELEMS);
        #pragma unroll
        for (int i = 0; i < 4; ++i) {
            int idx = i * 256 + tid;
            int d = idx >> 4, f8 = (idx & 15) * 8;
            *(uint4*)&Bv[d * SV + 64 + f8] = s4g[idx];
        }
        if (tid < 16)
            *(uint4*)&Bk[64 * SB + tid * 8] =
                ((const uint4*)(wsks + (size_t)(h * NCHUNK + c) * 128))[tid];
    }
    __syncthreads();

    const int l0 = wave * 16;
    const int arow = (l0 + lrow) * SA;

    // GEMM1: scores + denominator
    short8 a1[4];
    #pragma unroll
    for (int ks = 0; ks < 4; ++ks)
        a1[ks] = *(const short8*)&Aq[arow + 64 + ks * 32 + quad * 8];
    floatx4 rs = {0.f, 0.f, 0.f, 0.f};
    #pragma unroll
    for (int nt = 0; nt < 5; ++nt) {
        floatx4 acc = {0.f, 0.f, 0.f, 0.f};
        #pragma unroll
        for (int ks = 0; ks < 4; ++ks) {
            short8 bf = *(const short8*)&Bk[(nt * 16 + lrow) * SB + ks * 32 + quad * 8];
            acc = __builtin_amdgcn_mfma_f32_16x16x32_bf16(a1[ks], bf, acc, 0, 0, 0);
        }
        if (nt < 4) {
            int j = nt * 16 + lrow;
            #pragma unroll
            for (int r = 0; r < 4; ++r) {
                int l = l0 + quad * 4 + r;
                float m = (j <= l) ? acc[r] : 0.f;
                acc[r] = m;
                Aq[l * SA + j] = f2bf(m);      // masked score -> A-layout for GEMM2
            }
        }
        rs += acc;                              // nt==4: cols 65..79 are exact zeros
    }
    #pragma unroll
    for (int m = 1; m <= 8; m <<= 1) {          // row-sum across the 16 cols
        rs[0] += __shfl_xor(rs[0], m);
        rs[1] += __shfl_xor(rs[1], m);
        rs[2] += __shfl_xor(rs[2], m);
        rs[3] += __shfl_xor(rs[3], m);
    }
    float inv[4];
    #pragma unroll
    for (int r = 0; r < 4; ++r) inv[r] = 1.0f / fmaxf(rs[r], EPSV);

    __syncthreads();   // make this wave's score writes unambiguously visible

    // GEMM2: O = [scores | qf] * [V ; S]
    short8 s0 = *(const short8*)&Aq[arow + 0 * 32 + quad * 8];
    short8 s1 = *(const short8*)&Aq[arow + 1 * 32 + quad * 8];
    #pragma unroll
    for (int nt = 0; nt < 4; ++nt) {
        const int brow = (nt * 16 + lrow) * SV;
        floatx4 acc = {0.f, 0.f, 0.f, 0.f};
        short8 b0 = *(const short8*)&Bv[brow + 0 * 32 + quad * 8];
        acc = __builtin_amdgcn_mfma_f32_16x16x32_bf16(s0, b0, acc, 0, 0, 0);
        short8 b1 = *(const short8*)&Bv[brow + 1 * 32 + quad * 8];
        acc = __builtin_amdgcn_mfma_f32_16x16x32_bf16(s1, b1, acc, 0, 0, 0);
        #pragma unroll
        for (int ks = 2; ks < 6; ++ks) {
            short8 bf = *(const short8*)&Bv[brow + ks * 32 + quad * 8];
            acc = __builtin_amdgcn_mfma_f32_16x16x32_bf16(a1[ks - 2], bf, acc, 0, 0, 0);
        }
        #pragma unroll
        for (int r = 0; r < 4; ++r) {
            int l = l0 + quad * 4 + r;
            out[gbase + (size_t)l * Dd + nt * 16 + lrow] = acc[r] * inv[r];
        }
    }
}

extern "C" void kernel_launch(void* const* d_in, const int* in_sizes, int n_in,
                              void* d_out, int out_size, void* d_ws, size_t ws_size,
                              hipStream_t stream) {
    const float* q = (const float*)d_in[0];
    const float* k = (const float*)d_in[1];
    const float* v = (const float*)d_in[2];
    float* out = (float*)d_out;
    unsigned short* wskv = (unsigned short*)d_ws;             // [h][c][d][f] bf16
    unsigned short* wsks = wskv + KV_TOTAL_E;                 // [h][c][128] bf16
    dim3 grid(NCHUNK, Hh), block(256, 1, 1);
    void* args[] = {(void*)&q, (void*)&k, (void*)&v,
                    (void*)&wskv, (void*)&wsks, (void*)&out};
    hipLaunchCooperativeKernel((const void*)cf_fused, grid, block, args, 0, stream);
}

// Round 2
// 94.477 us; speedup vs baseline: 2.1229x; 2.1229x over previous
//
#include <hip/hip_runtime.h>

namespace {
constexpr int Hh = 16;
constexpr int Ll = 1024;
constexpr int Dd = 64;
constexpr int Cc = 64;                   // chunk length
constexpr int NCHUNK = Ll / Cc;          // 16
constexpr float PI_HALF = 1.5707963267948966f;
constexpr float EPSV = 1e-6f;
}

typedef __attribute__((ext_vector_type(8))) short short8;
typedef __attribute__((ext_vector_type(4))) float floatx4;

__device__ __forceinline__ unsigned short f2bf(float x) {
    unsigned int u = __float_as_uint(x);
    unsigned int r = u + 0x7fffu + ((u >> 16) & 1u);
    return (unsigned short)(r >> 16);
}

// ---------------------------------------------------------------------------
// Single plain launch, one block per (h,c), ZERO inter-block communication.
//
// Block (h,c):
//   Loop cp = 0..c-1: stage kf^T(cp) -> Ak, [V^T(cp);1] -> Bvv (reg-prefetched),
//     MFMA-accumulate exclusive state S[f][d] (+ ksum via ones column) into
//     PERSISTENT accumulators acc[2][5] (fp32, the native phase-A fragment
//     layout). 2 barriers/iter; next chunk's k/v global loads are issued right
//     after the LDS write so HBM latency hides under the MFMAs.
//   Epilogue (the proven cf_out): stage q,k,v of own chunk; dump acc -> bf16
//     into Bv cols 64.. (state) and Bk row 64 (ksum); GEMM1 (scores+denom),
//     mask + shfl rowsum, GEMM2, store.
//
// vs round 1: no grid.sync, no __threadfence (no per-XCD L2 flushes), no
// workspace. Redundant prior-chunk reads are L2/L3-served (inputs = 12 MB).
__global__ __launch_bounds__(256)
void cf_onego(const float* __restrict__ qin, const float* __restrict__ kin,
              const float* __restrict__ vin, float* __restrict__ out) {
    const int c = blockIdx.x, h = blockIdx.y;
    const int tid = threadIdx.x;
    constexpr int SA = 200, SB = 136, SV = 200, S1 = 72;
    __shared__ unsigned short Ak[128 * S1];   // loop: kf^T [f][j]
    __shared__ unsigned short Bvv[80 * S1];   // loop: [n=d][k=j]; row 64 = ones
    __shared__ unsigned short Aq[64 * SA];    // [l][0..63 scores | 64..191 qf]
    __shared__ unsigned short Bk[80 * SB];    // [n=j][k=f]; row 64 = ksum; 65..79 = 0
    __shared__ unsigned short Bv[64 * SV];    // [n=d][0..63 V^T | 64..191 S]

    const int wave = tid >> 6, lane = tid & 63;
    const int lrow = lane & 15, quad = lane >> 4;

    // one-time constant rows (buffers untouched by the per-chunk rewrites)
    if (tid < 64) Bvv[64 * S1 + tid] = 0x3F80;           // ones row (bf16 1.0)
    if (tid >= 64 && tid < 72) Bvv[64 * S1 + tid] = 0;
    #pragma unroll
    for (int i = 0; i < 3; ++i) {                        // zero Bvv rows 65..79
        int z = i * 256 + tid;
        if (z < 540) ((unsigned int*)Bvv)[(65 * S1) / 2 + z] = 0u;
    }
    #pragma unroll
    for (int i = 0; i < 4; ++i) {                        // zero Bk rows 65..79
        int z = i * 256 + tid;
        if (z < 1020) ((unsigned int*)Bk)[(65 * SB) / 2 + z] = 0u;
    }

    // persistent exclusive-state accumulators: acc[t][nt], f-tile ft=wave*2+t
    floatx4 acc[2][5];
    #pragma unroll
    for (int t = 0; t < 2; ++t)
        #pragma unroll
        for (int nt = 0; nt < 5; ++nt)
            acc[t][nt] = (floatx4){0.f, 0.f, 0.f, 0.f};

    // ---- exclusive-prefix state loop over previous chunks ----
    float4 kreg[4], vreg[4];
    if (c > 0) {
        const float4* k4 = (const float4*)(kin + (size_t)h * Ll * Dd);
        const float4* v4 = (const float4*)(vin + (size_t)h * Ll * Dd);
        #pragma unroll
        for (int i = 0; i < 4; ++i) {
            kreg[i] = k4[i * 256 + tid];
            vreg[i] = v4[i * 256 + tid];
        }
    }
    for (int cp = 0; cp < c; ++cp) {
        if (cp) __syncthreads();        // prior MFMAs done reading Ak/Bvv
        #pragma unroll
        for (int i = 0; i < 4; ++i) {
            int e4 = i * 256 + tid;
            int j = e4 >> 4, d4 = (e4 & 15) * 4;
            float th = PI_HALF * (float)(cp * Cc + j + 1) * (1.0f / (float)Ll);
            float sj, cj; __sincosf(th, &sj, &cj);
            float4 kx = kreg[i];
            float r0 = fmaxf(kx.x, 0.f), r1 = fmaxf(kx.y, 0.f);
            float r2 = fmaxf(kx.z, 0.f), r3 = fmaxf(kx.w, 0.f);
            Ak[(d4 + 0) * S1 + j] = f2bf(r0 * sj);
            Ak[(d4 + 1) * S1 + j] = f2bf(r1 * sj);
            Ak[(d4 + 2) * S1 + j] = f2bf(r2 * sj);
            Ak[(d4 + 3) * S1 + j] = f2bf(r3 * sj);
            Ak[(64 + d4 + 0) * S1 + j] = f2bf(r0 * cj);
            Ak[(64 + d4 + 1) * S1 + j] = f2bf(r1 * cj);
            Ak[(64 + d4 + 2) * S1 + j] = f2bf(r2 * cj);
            Ak[(64 + d4 + 3) * S1 + j] = f2bf(r3 * cj);
            float4 vx = vreg[i];
            Bvv[(d4 + 0) * S1 + j] = f2bf(vx.x);
            Bvv[(d4 + 1) * S1 + j] = f2bf(vx.y);
            Bvv[(d4 + 2) * S1 + j] = f2bf(vx.z);
            Bvv[(d4 + 3) * S1 + j] = f2bf(vx.w);
        }
        __syncthreads();
        if (cp + 1 < c) {               // prefetch next chunk; hides under MFMA
            const float4* k4 =
                (const float4*)(kin + ((size_t)h * Ll + (size_t)(cp + 1) * Cc) * Dd);
            const float4* v4 =
                (const float4*)(vin + ((size_t)h * Ll + (size_t)(cp + 1) * Cc) * Dd);
            #pragma unroll
            for (int i = 0; i < 4; ++i) {
                kreg[i] = k4[i * 256 + tid];
                vreg[i] = v4[i * 256 + tid];
            }
        }
        #pragma unroll
        for (int t = 0; t < 2; ++t) {
            const int ft = wave * 2 + t;
            short8 af0 = *(const short8*)&Ak[(ft * 16 + lrow) * S1 + quad * 8];
            short8 af1 = *(const short8*)&Ak[(ft * 16 + lrow) * S1 + 32 + quad * 8];
            #pragma unroll
            for (int nt = 0; nt < 5; ++nt) {
                short8 b0 = *(const short8*)&Bvv[(nt * 16 + lrow) * S1 + quad * 8];
                short8 b1 = *(const short8*)&Bvv[(nt * 16 + lrow) * S1 + 32 + quad * 8];
                acc[t][nt] = __builtin_amdgcn_mfma_f32_16x16x32_bf16(af0, b0, acc[t][nt], 0, 0, 0);
                acc[t][nt] = __builtin_amdgcn_mfma_f32_16x16x32_bf16(af1, b1, acc[t][nt], 0, 0, 0);
            }
        }
    }

    // ---- epilogue: stage own chunk, dump state, GEMM1 + GEMM2 ----
    const size_t gbase = ((size_t)h * Ll + (size_t)c * Cc) * Dd;
    const float4* q4 = (const float4*)(qin + gbase);
    const float4* k4 = (const float4*)(kin + gbase);
    const float4* v4 = (const float4*)(vin + gbase);
    #pragma unroll
    for (int i = 0; i < 4; ++i) {
        int e4 = i * 256 + tid;
        int j = e4 >> 4, d4 = (e4 & 15) * 4;
        float th = PI_HALF * (float)(c * Cc + j + 1) * (1.0f / (float)Ll);
        float sj, cj; __sincosf(th, &sj, &cj);
        float4 qv = q4[e4];
        float q0 = fmaxf(qv.x, 0.f), q1 = fmaxf(qv.y, 0.f);
        float q2 = fmaxf(qv.z, 0.f), q3 = fmaxf(qv.w, 0.f);
        *(ushort4*)&Aq[j * SA + 64 + d4] =
            make_ushort4(f2bf(q0 * sj), f2bf(q1 * sj), f2bf(q2 * sj), f2bf(q3 * sj));
        *(ushort4*)&Aq[j * SA + 128 + d4] =
            make_ushort4(f2bf(q0 * cj), f2bf(q1 * cj), f2bf(q2 * cj), f2bf(q3 * cj));
        float4 kx = k4[e4];
        float k0 = fmaxf(kx.x, 0.f), k1 = fmaxf(kx.y, 0.f);
        float k2 = fmaxf(kx.z, 0.f), k3 = fmaxf(kx.w, 0.f);
        *(ushort4*)&Bk[j * SB + d4] =
            make_ushort4(f2bf(k0 * sj), f2bf(k1 * sj), f2bf(k2 * sj), f2bf(k3 * sj));
        *(ushort4*)&Bk[j * SB + 64 + d4] =
            make_ushort4(f2bf(k0 * cj), f2bf(k1 * cj), f2bf(k2 * cj), f2bf(k3 * cj));
        float4 vx = v4[e4];
        Bv[(d4 + 0) * SV + j] = f2bf(vx.x);
        Bv[(d4 + 1) * SV + j] = f2bf(vx.y);
        Bv[(d4 + 2) * SV + j] = f2bf(vx.z);
        Bv[(d4 + 3) * SV + j] = f2bf(vx.w);
    }
    // dump exclusive state S[f][d] -> Bv[d][64+f] (bf16), ksum -> Bk row 64
    #pragma unroll
    for (int t = 0; t < 2; ++t) {
        const int ft = wave * 2 + t;
        #pragma unroll
        for (int nt = 0; nt < 4; ++nt) {
            *(ushort4*)&Bv[(nt * 16 + lrow) * SV + 64 + ft * 16 + quad * 4] =
                make_ushort4(f2bf(acc[t][nt][0]), f2bf(acc[t][nt][1]),
                             f2bf(acc[t][nt][2]), f2bf(acc[t][nt][3]));
        }
        if (lrow == 0)
            *(ushort4*)&Bk[64 * SB + ft * 16 + quad * 4] =
                make_ushort4(f2bf(acc[t][4][0]), f2bf(acc[t][4][1]),
                             f2bf(acc[t][4][2]), f2bf(acc[t][4][3]));
    }
    __syncthreads();

    const int l0 = wave * 16;
    const int arow = (l0 + lrow) * SA;

    // GEMM1: scores + denominator
    short8 a1[4];
    #pragma unroll
    for (int ks = 0; ks < 4; ++ks)
        a1[ks] = *(const short8*)&Aq[arow + 64 + ks * 32 + quad * 8];
    floatx4 rs = {0.f, 0.f, 0.f, 0.f};
    #pragma unroll
    for (int nt = 0; nt < 5; ++nt) {
        floatx4 sc = {0.f, 0.f, 0.f, 0.f};
        #pragma unroll
        for (int ks = 0; ks < 4; ++ks) {
            short8 bf = *(const short8*)&Bk[(nt * 16 + lrow) * SB + ks * 32 + quad * 8];
            sc = __builtin_amdgcn_mfma_f32_16x16x32_bf16(a1[ks], bf, sc, 0, 0, 0);
        }
        if (nt < 4) {
            int j = nt * 16 + lrow;
            #pragma unroll
            for (int r = 0; r < 4; ++r) {
                int l = l0 + quad * 4 + r;
                float m = (j <= l) ? sc[r] : 0.f;
                sc[r] = m;
                Aq[l * SA + j] = f2bf(m);      // masked score -> A-layout for GEMM2
            }
        }
        rs += sc;                               // nt==4: cols 65..79 are exact zeros
    }
    #pragma unroll
    for (int m = 1; m <= 8; m <<= 1) {          // row-sum across the 16 cols
        rs[0] += __shfl_xor(rs[0], m);
        rs[1] += __shfl_xor(rs[1], m);
        rs[2] += __shfl_xor(rs[2], m);
        rs[3] += __shfl_xor(rs[3], m);
    }
    float inv[4];
    #pragma unroll
    for (int r = 0; r < 4; ++r) inv[r] = 1.0f / fmaxf(rs[r], EPSV);

    __syncthreads();   // make this wave's score writes unambiguously visible

    // GEMM2: O = [scores | qf] * [V ; S]
    short8 sc0 = *(const short8*)&Aq[arow + 0 * 32 + quad * 8];
    short8 sc1 = *(const short8*)&Aq[arow + 1 * 32 + quad * 8];
    #pragma unroll
    for (int nt = 0; nt < 4; ++nt) {
        const int brow = (nt * 16 + lrow) * SV;
        floatx4 oacc = {0.f, 0.f, 0.f, 0.f};
        short8 b0 = *(const short8*)&Bv[brow + 0 * 32 + quad * 8];
        oacc = __builtin_amdgcn_mfma_f32_16x16x32_bf16(sc0, b0, oacc, 0, 0, 0);
        short8 b1 = *(const short8*)&Bv[brow + 1 * 32 + quad * 8];
        oacc = __builtin_amdgcn_mfma_f32_16x16x32_bf16(sc1, b1, oacc, 0, 0, 0);
        #pragma unroll
        for (int ks = 2; ks < 6; ++ks) {
            short8 bf = *(const short8*)&Bv[brow + ks * 32 + quad * 8];
            oacc = __builtin_amdgcn_mfma_f32_16x16x32_bf16(a1[ks - 2], bf, oacc, 0, 0, 0);
        }
        #pragma unroll
        for (int r = 0; r < 4; ++r) {
            int l = l0 + quad * 4 + r;
            out[gbase + (size_t)l * Dd + nt * 16 + lrow] = oacc[r] * inv[r];
        }
    }
}

extern "C" void kernel_launch(void* const* d_in, const int* in_sizes, int n_in,
                              void* d_out, int out_size, void* d_ws, size_t ws_size,
                              hipStream_t stream) {
    const float* q = (const float*)d_in[0];
    const float* k = (const float*)d_in[1];
    const float* v = (const float*)d_in[2];
    float* out = (float*)d_out;
    dim3 grid(NCHUNK, Hh);
    cf_onego<<<grid, 256, 0, stream>>>(q, k, v, out);
}

// Round 4
// 90.086 us; speedup vs baseline: 2.2264x; 1.0487x over previous
//
#include <hip/hip_runtime.h>

namespace {
constexpr int Hh = 16;
constexpr int Ll = 1024;
constexpr int Dd = 64;
constexpr int Cc = 64;                   // chunk length
constexpr int NCHUNK = Ll / Cc;          // 16
constexpr float PI_HALF = 1.5707963267948966f;
constexpr float EPSV = 1e-6f;
}

typedef __attribute__((ext_vector_type(8))) short short8;
typedef __attribute__((ext_vector_type(4))) float floatx4;

__device__ __forceinline__ unsigned short f2bf(float x) {
    unsigned int u = __float_as_uint(x);
    unsigned int r = u + 0x7fffu + ((u >> 16) & 1u);
    return (unsigned short)(r >> 16);
}

// ---------------------------------------------------------------------------
// Kernel P: one-time feature-map + transpose into ws (bf16):
//   kfT[h][f=128][j=1024] : kf^T, rows contiguous along j
//   vT [h][d=64 ][j=1024] : V^T
// Round-3 bug fixed here: kfT needs 1024 uint4 stores (128x64 elems), vT needs
// 512 (64x64) — previous version wrote half/quarter, leaving poisoned rows.
__global__ __launch_bounds__(256)
void cf_prep(const float* __restrict__ kin, const float* __restrict__ vin,
             unsigned short* __restrict__ kfT, unsigned short* __restrict__ vT) {
    const int jt = blockIdx.x, h = blockIdx.y;
    const int tid = threadIdx.x;
    constexpr int S1 = 72;
    __shared__ unsigned short AkT[128 * S1];
    __shared__ unsigned short Vt[64 * S1];

    const size_t gbase = ((size_t)h * Ll + (size_t)jt * Cc) * Dd;
    const float4* k4 = (const float4*)(kin + gbase);
    const float4* v4 = (const float4*)(vin + gbase);
    #pragma unroll
    for (int i = 0; i < 4; ++i) {
        int e4 = i * 256 + tid;
        int j = e4 >> 4, d4 = (e4 & 15) * 4;
        float th = PI_HALF * (float)(jt * Cc + j + 1) * (1.0f / (float)Ll);
        float sj, cj; __sincosf(th, &sj, &cj);
        float4 kx = k4[e4];
        float r0 = fmaxf(kx.x, 0.f), r1 = fmaxf(kx.y, 0.f);
        float r2 = fmaxf(kx.z, 0.f), r3 = fmaxf(kx.w, 0.f);
        AkT[(d4 + 0) * S1 + j] = f2bf(r0 * sj);
        AkT[(d4 + 1) * S1 + j] = f2bf(r1 * sj);
        AkT[(d4 + 2) * S1 + j] = f2bf(r2 * sj);
        AkT[(d4 + 3) * S1 + j] = f2bf(r3 * sj);
        AkT[(64 + d4 + 0) * S1 + j] = f2bf(r0 * cj);
        AkT[(64 + d4 + 1) * S1 + j] = f2bf(r1 * cj);
        AkT[(64 + d4 + 2) * S1 + j] = f2bf(r2 * cj);
        AkT[(64 + d4 + 3) * S1 + j] = f2bf(r3 * cj);
        float4 vx = v4[e4];
        Vt[(d4 + 0) * S1 + j] = f2bf(vx.x);
        Vt[(d4 + 1) * S1 + j] = f2bf(vx.y);
        Vt[(d4 + 2) * S1 + j] = f2bf(vx.z);
        Vt[(d4 + 3) * S1 + j] = f2bf(vx.w);
    }
    __syncthreads();

    unsigned short* kout = kfT + (size_t)h * 128 * Ll + jt * Cc;
    #pragma unroll
    for (int i = 0; i < 4; ++i) {                 // 128 rows x 8 uint4 = 1024 uint4
        int idx = i * 256 + tid;
        int row = idx >> 3, c8 = (idx & 7) * 8;
        *(uint4*)(kout + (size_t)row * Ll + c8) = *(const uint4*)&AkT[row * S1 + c8];
    }
    unsigned short* vout = vT + (size_t)h * 64 * Ll + jt * Cc;
    #pragma unroll
    for (int i = 0; i < 2; ++i) {                 // 64 rows x 8 uint4 = 512 uint4
        int idx = i * 256 + tid;
        int row = idx >> 3, c8 = (idx & 7) * 8;
        *(uint4*)(vout + (size_t)row * Ll + c8) = *(const uint4*)&Vt[row * S1 + c8];
    }
}

// ---------------------------------------------------------------------------
// Kernel M: one block per (h,c), zero inter-block communication.
//  Prefix state: K = c*64 GEMM with fragments loaded DIRECTLY from global
//  kfT/vT (no LDS, no barriers; L1/L2 serve reuse). ksum via constant ones
//  B-fragment. Then the round-2-verified epilogue: stage qf/kf from fp32,
//  Bv's V^T copied from vT, acc-dump, GEMM1 + mask + rowsum, GEMM2, store.
__global__ __launch_bounds__(256)
void cf_main(const float* __restrict__ qin, const float* __restrict__ kin,
             const unsigned short* __restrict__ kfT,
             const unsigned short* __restrict__ vT,
             float* __restrict__ out) {
    const int c = blockIdx.x, h = blockIdx.y;
    const int tid = threadIdx.x;
    constexpr int SA = 200, SB = 136, SV = 200;
    __shared__ unsigned short Aq[64 * SA];   // [l][0..63 scores | 64..191 qf]
    __shared__ unsigned short Bk[80 * SB];   // [n=j][k=f]; row 64 = ksum; 65..79 = 0
    __shared__ unsigned short Bv[64 * SV];   // [n=d][0..63 V^T | 64..191 S]

    const int wave = tid >> 6, lane = tid & 63;
    const int lrow = lane & 15, quad = lane >> 4;

    #pragma unroll
    for (int i = 0; i < 4; ++i) {            // zero Bk rows 65..79
        int z = i * 256 + tid;
        if (z < 1020) ((unsigned int*)Bk)[(65 * SB) / 2 + z] = 0u;
    }

    // ---- prefix state GEMM, fragments direct from global ----
    floatx4 acc[2][5];
    #pragma unroll
    for (int t = 0; t < 2; ++t)
        #pragma unroll
        for (int nt = 0; nt < 5; ++nt)
            acc[t][nt] = (floatx4){0.f, 0.f, 0.f, 0.f};

    const unsigned short* At = kfT + (size_t)h * 128 * Ll;
    const unsigned short* Bt = vT + (size_t)h * 64 * Ll;
    short8 bones;
    {
        short o = (lrow == 0) ? (short)0x3F80 : (short)0;
        #pragma unroll
        for (int i = 0; i < 8; ++i) bones[i] = o;
    }
    const int nk = c * Cc;
    const int a0 = (wave * 32 + lrow) * Ll + quad * 8;      // f-tile wave*2
    const int a1 = a0 + 16 * Ll;                             // f-tile wave*2+1
    const int br0 = (0 * 16 + lrow) * Ll + quad * 8;
    const int br1 = (1 * 16 + lrow) * Ll + quad * 8;
    const int br2 = (2 * 16 + lrow) * Ll + quad * 8;
    const int br3 = (3 * 16 + lrow) * Ll + quad * 8;

    if (nk > 0) {
        short8 af0 = *(const short8*)(At + a0);
        short8 af1 = *(const short8*)(At + a1);
        short8 vb0 = *(const short8*)(Bt + br0);
        short8 vb1 = *(const short8*)(Bt + br1);
        short8 vb2 = *(const short8*)(Bt + br2);
        short8 vb3 = *(const short8*)(Bt + br3);
        for (int kk = 0; kk < nk; kk += 32) {
            const int nx = kk + 32;
            short8 naf0 = af0, naf1 = af1;
            short8 nb0 = vb0, nb1 = vb1, nb2 = vb2, nb3 = vb3;
            if (nx < nk) {                       // prefetch next K-slice
                naf0 = *(const short8*)(At + a0 + nx);
                naf1 = *(const short8*)(At + a1 + nx);
                nb0 = *(const short8*)(Bt + br0 + nx);
                nb1 = *(const short8*)(Bt + br1 + nx);
                nb2 = *(const short8*)(Bt + br2 + nx);
                nb3 = *(const short8*)(Bt + br3 + nx);
            }
            acc[0][0] = __builtin_amdgcn_mfma_f32_16x16x32_bf16(af0, vb0, acc[0][0], 0, 0, 0);
            acc[0][1] = __builtin_amdgcn_mfma_f32_16x16x32_bf16(af0, vb1, acc[0][1], 0, 0, 0);
            acc[0][2] = __builtin_amdgcn_mfma_f32_16x16x32_bf16(af0, vb2, acc[0][2], 0, 0, 0);
            acc[0][3] = __builtin_amdgcn_mfma_f32_16x16x32_bf16(af0, vb3, acc[0][3], 0, 0, 0);
            acc[0][4] = __builtin_amdgcn_mfma_f32_16x16x32_bf16(af0, bones, acc[0][4], 0, 0, 0);
            acc[1][0] = __builtin_amdgcn_mfma_f32_16x16x32_bf16(af1, vb0, acc[1][0], 0, 0, 0);
            acc[1][1] = __builtin_amdgcn_mfma_f32_16x16x32_bf16(af1, vb1, acc[1][1], 0, 0, 0);
            acc[1][2] = __builtin_amdgcn_mfma_f32_16x16x32_bf16(af1, vb2, acc[1][2], 0, 0, 0);
            acc[1][3] = __builtin_amdgcn_mfma_f32_16x16x32_bf16(af1, vb3, acc[1][3], 0, 0, 0);
            acc[1][4] = __builtin_amdgcn_mfma_f32_16x16x32_bf16(af1, bones, acc[1][4], 0, 0, 0);
            af0 = naf0; af1 = naf1;
            vb0 = nb0; vb1 = nb1; vb2 = nb2; vb3 = nb3;
        }
    }

    // ---- epilogue: stage own chunk, dump state, GEMM1 + GEMM2 ----
    const size_t gbase = ((size_t)h * Ll + (size_t)c * Cc) * Dd;
    const float4* q4 = (const float4*)(qin + gbase);
    const float4* k4 = (const float4*)(kin + gbase);
    #pragma unroll
    for (int i = 0; i < 4; ++i) {
        int e4 = i * 256 + tid;
        int j = e4 >> 4, d4 = (e4 & 15) * 4;
        float th = PI_HALF * (float)(c * Cc + j + 1) * (1.0f / (float)Ll);
        float sj, cj; __sincosf(th, &sj, &cj);
        float4 qv = q4[e4];
        float q0 = fmaxf(qv.x, 0.f), q1 = fmaxf(qv.y, 0.f);
        float q2 = fmaxf(qv.z, 0.f), q3 = fmaxf(qv.w, 0.f);
        *(ushort4*)&Aq[j * SA + 64 + d4] =
            make_ushort4(f2bf(q0 * sj), f2bf(q1 * sj), f2bf(q2 * sj), f2bf(q3 * sj));
        *(ushort4*)&Aq[j * SA + 128 + d4] =
            make_ushort4(f2bf(q0 * cj), f2bf(q1 * cj), f2bf(q2 * cj), f2bf(q3 * cj));
        float4 kx = k4[e4];
        float k0 = fmaxf(kx.x, 0.f), k1 = fmaxf(kx.y, 0.f);
        float k2 = fmaxf(kx.z, 0.f), k3 = fmaxf(kx.w, 0.f);
        *(ushort4*)&Bk[j * SB + d4] =
            make_ushort4(f2bf(k0 * sj), f2bf(k1 * sj), f2bf(k2 * sj), f2bf(k3 * sj));
        *(ushort4*)&Bk[j * SB + 64 + d4] =
            make_ushort4(f2bf(k0 * cj), f2bf(k1 * cj), f2bf(k2 * cj), f2bf(k3 * cj));
    }
    // Bv cols 0..63 = V^T of own chunk, straight bf16 copy from vT
    const unsigned short* vsrc = Bt + c * Cc;
    #pragma unroll
    for (int i = 0; i < 2; ++i) {                 // 64 rows x 8 uint4 = 512 uint4
        int idx = i * 256 + tid;
        int d = idx >> 3, j8 = (idx & 7) * 8;
        *(uint4*)&Bv[d * SV + j8] = *(const uint4*)(vsrc + (size_t)d * Ll + j8);
    }
    // dump exclusive state S[f][d] -> Bv[d][64+f] (bf16), ksum -> Bk row 64
    #pragma unroll
    for (int t = 0; t < 2; ++t) {
        const int ft = wave * 2 + t;
        #pragma unroll
        for (int nt = 0; nt < 4; ++nt) {
            *(ushort4*)&Bv[(nt * 16 + lrow) * SV + 64 + ft * 16 + quad * 4] =
                make_ushort4(f2bf(acc[t][nt][0]), f2bf(acc[t][nt][1]),
                             f2bf(acc[t][nt][2]), f2bf(acc[t][nt][3]));
        }
        if (lrow == 0)
            *(ushort4*)&Bk[64 * SB + ft * 16 + quad * 4] =
                make_ushort4(f2bf(acc[t][4][0]), f2bf(acc[t][4][1]),
                             f2bf(acc[t][4][2]), f2bf(acc[t][4][3]));
    }
    __syncthreads();

    const int l0 = wave * 16;
    const int arow = (l0 + lrow) * SA;

    // GEMM1: scores + denominator
    short8 a1f[4];
    #pragma unroll
    for (int ks = 0; ks < 4; ++ks)
        a1f[ks] = *(const short8*)&Aq[arow + 64 + ks * 32 + quad * 8];
    floatx4 rs = {0.f, 0.f, 0.f, 0.f};
    #pragma unroll
    for (int nt = 0; nt < 5; ++nt) {
        floatx4 sc = {0.f, 0.f, 0.f, 0.f};
        #pragma unroll
        for (int ks = 0; ks < 4; ++ks) {
            short8 bf = *(const short8*)&Bk[(nt * 16 + lrow) * SB + ks * 32 + quad * 8];
            sc = __builtin_amdgcn_mfma_f32_16x16x32_bf16(a1f[ks], bf, sc, 0, 0, 0);
        }
        if (nt < 4) {
            int j = nt * 16 + lrow;
            #pragma unroll
            for (int r = 0; r < 4; ++r) {
                int l = l0 + quad * 4 + r;
                float m = (j <= l) ? sc[r] : 0.f;
                sc[r] = m;
                Aq[l * SA + j] = f2bf(m);      // masked score -> A-layout for GEMM2
            }
        }
        rs += sc;                               // nt==4: rows 65..79 are exact zeros
    }
    #pragma unroll
    for (int m = 1; m <= 8; m <<= 1) {          // row-sum across the 16 cols
        rs[0] += __shfl_xor(rs[0], m);
        rs[1] += __shfl_xor(rs[1], m);
        rs[2] += __shfl_xor(rs[2], m);
        rs[3] += __shfl_xor(rs[3], m);
    }
    float inv[4];
    #pragma unroll
    for (int r = 0; r < 4; ++r) inv[r] = 1.0f / fmaxf(rs[r], EPSV);

    __syncthreads();   // make this wave's score writes unambiguously visible

    // GEMM2: O = [scores | qf] * [V ; S]
    short8 sc0 = *(const short8*)&Aq[arow + 0 * 32 + quad * 8];
    short8 sc1 = *(const short8*)&Aq[arow + 1 * 32 + quad * 8];
    #pragma unroll
    for (int nt = 0; nt < 4; ++nt) {
        const int brow = (nt * 16 + lrow) * SV;
        floatx4 oacc = {0.f, 0.f, 0.f, 0.f};
        short8 b0 = *(const short8*)&Bv[brow + 0 * 32 + quad * 8];
        oacc = __builtin_amdgcn_mfma_f32_16x16x32_bf16(sc0, b0, oacc, 0, 0, 0);
        short8 b1 = *(const short8*)&Bv[brow + 1 * 32 + quad * 8];
        oacc = __builtin_amdgcn_mfma_f32_16x16x32_bf16(sc1, b1, oacc, 0, 0, 0);
        #pragma unroll
        for (int ks = 2; ks < 6; ++ks) {
            short8 bf = *(const short8*)&Bv[brow + ks * 32 + quad * 8];
            oacc = __builtin_amdgcn_mfma_f32_16x16x32_bf16(a1f[ks - 2], bf, oacc, 0, 0, 0);
        }
        #pragma unroll
        for (int r = 0; r < 4; ++r) {
            int l = l0 + quad * 4 + r;
            out[gbase + (size_t)l * Dd + nt * 16 + lrow] = oacc[r] * inv[r];
        }
    }
}

extern "C" void kernel_launch(void* const* d_in, const int* in_sizes, int n_in,
                              void* d_out, int out_size, void* d_ws, size_t ws_size,
                              hipStream_t stream) {
    const float* q = (const float*)d_in[0];
    const float* k = (const float*)d_in[1];
    const float* v = (const float*)d_in[2];
    float* out = (float*)d_out;
    unsigned short* kfT = (unsigned short*)d_ws;                  // [h][128][1024] bf16
    unsigned short* vT = kfT + (size_t)Hh * 128 * Ll;             // [h][64][1024] bf16
    dim3 grid(NCHUNK, Hh);
    cf_prep<<<grid, 256, 0, stream>>>(k, v, kfT, vT);
    cf_main<<<grid, 256, 0, stream>>>(q, k, kfT, vT, out);
}